// Round 7
// baseline (522.253 us; speedup 1.0000x reference)
//
#include <hip/hip_runtime.h>
#include <stdint.h>

// Round 14: MEASUREMENT ROUND — identical r13 pipeline, k_bin launched TWICE.
//  Four flat rounds (452/449/447/454) across large structural changes mean
//  my attribution of the ~204us kernel budget (454 - 250us harness fill+
//  restore) between k_bin and k_accum is unconstrained guesswork: the
//  top-5 counter cutoff (~158us) has never shown our kernels.
//  Second k_bin is idempotent: every chunk's stage[] is fully written (ranks
//  are a permutation of 0..cntE-1 under any atomic order), payload/pfxT are
//  rewritten with equivalent content, and k_accum sums order-insensitively.
//  Read: t_bin = dur_us(this) - 454; t_accum = 454 - 250 - t_bin - ~8.
//  Branch: t_bin >~100 -> attack k_bin's LDS-atomic/scatter path next;
//          t_bin <~70  -> k_accum ~135us (latency on 55B scattered segment
//          reads) -> restore long segments (CHUNK=4096 via TPB=512).
//
// payload word: tok<<24 | c<<20 | q20(wt), c = bucket&15. hist key = w>>20.
// ws: payload u32*n | pfxT u16[NG][B1] | partial u64[SLICES][NG][4096]

#define TPB 256
#define B1 8192
#define CHUNK 2048                 // B1*CHUNK = 2^24 = n
#define EVT (CHUNK / TPB)          // 8 events per thread (spill-free stash)
#define NBUCKET 2400
#define GACC 16                    // buckets per group
#define NG (NBUCKET / GACC)        // 150 groups
#define SLICES 8
#define RPS (B1 / SLICES)          // 1024 slocal rows per slice
#define RPW (RPS / 8)              // 128 rows per wave
#define HCELLS (GACC * 256)        // 4096 cells per group
#define ATPB 512                   // k_accum block size (8 waves)
#define OUT_CH_STRIDE 76800        // 256*300
#define OUT_DP_STRIDE 153600       // 2*256*300

// classify: quotient-reuse form. rem = v - floor(v/c)*c is exactly jnp.mod.
__device__ __forceinline__ void classify_full(const float4 e, const float t0,
                                              const float d_wt, const float d_dt,
                                              int& bucket, int& tok, float& wt) {
    const float c1 = (float)(319.0 / 20.0 + 1e-4);   // W/PW + B
    const float c2 = (float)(239.0 / 15.0 + 1e-4);   // H/PH + B
    const float fy = floorf(e.y / c1);
    const float fz = floorf(e.z / c2);
    const float remy = e.y - fy * c1;
    const float remz = e.z - fz * c2;
    const int pos = (int)(fy + fz * 20.0f);
    tok = (int)(floorf(remy) + floorf(remz) * 16.0f);
    const int dt = (int)floorf(4.0f * (e.x - t0) / d_dt);
    const int p  = (int)e.w;
    bucket = (dt * 2 + p) * 300 + pos;
    wt = (e.x - t0) / d_wt;
}

__global__ __launch_bounds__(TPB) void k_bin(const float4* __restrict__ x,
                                             uint32_t* __restrict__ payload,
                                             uint16_t* __restrict__ pfxT,
                                             int n) {
    __shared__ uint32_t stage[CHUNK];     // 8 KB
    __shared__ uint32_t cnt[NG];          // 600 B: group counts, then prefixes
    __shared__ uint32_t wsum[TPB / 64];   // 4 waves

    if (threadIdx.x < NG) cnt[threadIdx.x] = 0;
    __syncthreads();

    const float* xf = (const float*)x;
    const float t0 = xf[0];
    const float tlast = xf[(size_t)(n - 1) * 4];
    const float d_wt = tlast - t0 + 1e-4f;
    const float d_dt = tlast - t0 + 1.0f;

    const int beg = blockIdx.x * CHUNK;
    const bool full = (beg + CHUNK <= n);

    // phase 1: classify once; atomicAdd returns within-group rank (stash it)
    uint32_t pk[EVT];
    uint32_t bk[EVT];
    if (full) {
        #pragma unroll
        for (int k = 0; k < EVT; ++k) {
            float4 e = x[beg + threadIdx.x + k * TPB];
            int bucket, tok; float wt;
            classify_full(e, t0, d_wt, d_dt, bucket, tok, wt);
            uint32_t q = (uint32_t)(wt * 1048576.0f);          // q20
            q = q > 1048575u ? 1048575u : q;
            pk[k] = ((uint32_t)tok << 24) | ((uint32_t)(bucket & 15) << 20) | q;
            const int g = bucket >> 4;                         // /16 = group
            uint32_t rank = atomicAdd(&cnt[g], 1u);
            bk[k] = (uint32_t)g | (rank << 8);                 // group:8 rank:11
        }
    } else {
        #pragma unroll
        for (int k = 0; k < EVT; ++k) {
            const int i = beg + threadIdx.x + k * TPB;
            if (i < n) {
                float4 e = x[i];
                int bucket, tok; float wt;
                classify_full(e, t0, d_wt, d_dt, bucket, tok, wt);
                uint32_t q = (uint32_t)(wt * 1048576.0f);
                q = q > 1048575u ? 1048575u : q;
                pk[k] = ((uint32_t)tok << 24) | ((uint32_t)(bucket & 15) << 20) | q;
                const int g = bucket >> 4;
                uint32_t rank = atomicAdd(&cnt[g], 1u);
                bk[k] = (uint32_t)g | (rank << 8);
            } else {
                bk[k] = 0xFFFFFFFFu;
            }
        }
    }
    __syncthreads();

    // phase 2: exclusive scan of 150 group counts (threads 0..149)
    const uint32_t c = (threadIdx.x < NG) ? cnt[threadIdx.x] : 0u;
    uint32_t inc = c;
    #pragma unroll
    for (int off = 1; off < 64; off <<= 1) {
        uint32_t u = __shfl_up(inc, off, 64);
        if ((threadIdx.x & 63) >= off) inc += u;
    }
    const int wid = threadIdx.x >> 6, lid = threadIdx.x & 63;
    if (lid == 63) wsum[wid] = inc;
    __syncthreads();
    uint32_t woff = 0;
    for (int w = 0; w < wid; ++w) woff += wsum[w];
    const uint32_t excl = woff + inc - c;

    if (threadIdx.x < NG) {
        cnt[threadIdx.x] = excl;             // group start (read-only below)
        pfxT[(size_t)threadIdx.x * B1 + blockIdx.x] = (uint16_t)excl;
    }
    __syncthreads();

    // phase 3: plain indexed store (rank came from the phase-1 atomic)
    if (full) {
        #pragma unroll
        for (int k = 0; k < EVT; ++k)
            stage[cnt[bk[k] & 0xFFu] + (bk[k] >> 8)] = pk[k];
    } else {
        #pragma unroll
        for (int k = 0; k < EVT; ++k)
            if (bk[k] != 0xFFFFFFFFu)
                stage[cnt[bk[k] & 0xFFu] + (bk[k] >> 8)] = pk[k];
    }
    __syncthreads();

    // phase 4: coalesced LDS -> global writeout
    const int end = min(beg + CHUNK, n);
    const int cntE = end > beg ? end - beg : 0;
    uint32_t* pbase = payload + (size_t)blockIdx.x * CHUNK;
    const int n4 = cntE >> 2;
    const uint4* s4 = (const uint4*)stage;
    uint4* g4 = (uint4*)pbase;
    for (int i = threadIdx.x; i < n4; i += TPB) g4[i] = s4[i];
    for (int i = (n4 << 2) + threadIdx.x; i < cntE; i += TPB) pbase[i] = stage[i];
}

// One block per (group, slice): 150 x 8 = 1200 blocks. STRIDED rows (r12
// balance fix): slice s owns rows {slocal*8 + s} -> every slice samples all
// dt ranges. g=bid>>3, s=bid&7: (g,s)/(g+1,s) bids differ by 8 = 0 mod 8 ->
// same XCD for shared boundary lines. 8 waves x 128 rows (2 batches of 64);
// 16-lane quarters stream each row's payload span.
__global__ __launch_bounds__(ATPB) void k_accum(const uint32_t* __restrict__ payload,
                                                const uint16_t* __restrict__ pfxT,
                                                unsigned long long* __restrict__ partial,
                                                int n) {
    const int g = blockIdx.x >> 3;
    const int s = blockIdx.x & 7;

    __shared__ unsigned long long hist[HCELLS];   // 32 KB: (tok*16+c) -> cnt<<40 | q20sum
    for (int i = threadIdx.x; i < HCELLS; i += ATPB) hist[i] = 0ULL;
    __syncthreads();

    const uint16_t* colb = pfxT + (size_t)g * B1;
    const bool last = (g == NG - 1);
    const uint16_t* cole = colb + B1;             // valid iff !last

    const int wid = threadIdx.x >> 6, lid = threadIdx.x & 63;
    const int s0 = wid * RPW;                     // 8 waves x 128 slocal rows
    const int q4 = lid >> 4;                      // quarter 0..3
    const int ql = lid & 15;

    for (int h = 0; h < RPW; h += 64) {
        const int row = (s0 + h + lid) * SLICES + s;
        uint32_t vb = colb[row];
        uint32_t ve;
        if (!last) {
            ve = cole[row];
        } else {
            int rc = n - row * CHUNK;
            ve = rc < 0 ? 0 : (rc > CHUNK ? CHUNK : rc);
        }
        for (int r = 0; r < 64; r += 4) {
            const int rr = r + q4;
            const uint32_t sb = __shfl(vb, rr, 64);
            const uint32_t se = __shfl(ve, rr, 64);
            const uint32_t* seg = payload + (size_t)((s0 + h + rr) * SLICES + s) * CHUNK;
            for (uint32_t j = sb + ql; j < se; j += 16) {
                const uint32_t w = seg[j];
                atomicAdd(&hist[w >> 20],
                          (1ULL << 40) | (unsigned long long)(w & 0xFFFFFu));
            }
        }
    }
    __syncthreads();

    // coalesced partial writeout (every cell written -> no ws pre-zero)
    unsigned long long* pp = partial + ((size_t)s * NG + g) * HCELLS;
    for (int i = threadIdx.x; i < HCELLS; i += ATPB) pp[i] = hist[i];
}

// Sum 8 partials per cell; coalesced reads AND writes (consecutive cells ->
// consecutive pos because key = tok*16 + c). 614,400 cells, each out written
// exactly once -> no out memset.
__global__ __launch_bounds__(256) void k_out(const unsigned long long* __restrict__ partial,
                                             float* __restrict__ out) {
    const int i = blockIdx.x * 256 + threadIdx.x;   // cell id
    unsigned long long v = 0ULL;
    #pragma unroll
    for (int s = 0; s < SLICES; ++s)
        v += partial[(size_t)s * (NG * HCELLS) + i];
    const int g = i >> 12;
    const int idx = i & 4095;
    const int tok = idx >> 4;
    const int c = idx & 15;
    const int b = g * GACC + c;
    const int pos = b % 300;
    const int dp = b / 300;
    const float cntf = (float)(uint32_t)(v >> 40);
    const float wts  = (float)(v & ((1ULL << 40) - 1)) * (1.0f / 1048576.0f);
    const int base0 = dp * OUT_DP_STRIDE + tok * 300 + pos;
    out[base0] = cntf;                     // channel 0: count
    out[base0 + OUT_CH_STRIDE] = wts;      // channel 1: wt sum
}

// ---- fallback (ws too small / n out of range) ----
__global__ __launch_bounds__(256) void e2src_hist_atomic(const float4* __restrict__ x,
                                                         float* __restrict__ out, int n) {
    const float* xf = (const float*)x;
    const float t0 = xf[0];
    const float tlast = xf[(size_t)(n - 1) * 4];
    const float d_wt = tlast - t0 + 1e-4f;
    const float d_dt = tlast - t0 + 1.0f;
    int i = blockIdx.x * blockDim.x + threadIdx.x;
    const int stride = gridDim.x * blockDim.x;
    for (; i < n; i += stride) {
        float4 e = x[i];
        int bucket, tok; float wt;
        classify_full(e, t0, d_wt, d_dt, bucket, tok, wt);
        const int dp = bucket / 300, pos = bucket % 300;
        const int base = dp * OUT_DP_STRIDE + tok * 300 + pos;
        unsafeAtomicAdd(out + base, 1.0f);
        unsafeAtomicAdd(out + base + OUT_CH_STRIDE, wt);
    }
}

extern "C" void kernel_launch(void* const* d_in, const int* in_sizes, int n_in,
                              void* d_out, int out_size, void* d_ws, size_t ws_size,
                              hipStream_t stream) {
    const float* x = (const float*)d_in[0];
    float* out = (float*)d_out;
    const int n = in_sizes[0] / 4;

    const size_t payload_bytes = ((size_t)n * 4u + 7u) & ~(size_t)7u;
    const size_t pfx_bytes = (size_t)B1 * NG * 2u;                 // 2,457,600
    const size_t part_bytes = (size_t)SLICES * NG * HCELLS * 8u;   // 39,321,600
    const size_t need = payload_bytes + pfx_bytes + part_bytes;

    if (ws_size < need || n > B1 * CHUNK || n <= 0) {
        hipMemsetAsync(d_out, 0, (size_t)out_size * sizeof(float), stream);
        if (n > 0)
            hipLaunchKernelGGL(e2src_hist_atomic, dim3(8192), dim3(256), 0, stream,
                               (const float4*)x, out, n);
        return;
    }

    uint32_t* payload = (uint32_t*)d_ws;
    uint16_t* pfxT = (uint16_t*)((char*)d_ws + payload_bytes);
    unsigned long long* partial =
        (unsigned long long*)((char*)d_ws + payload_bytes + pfx_bytes);

    // MEASUREMENT: k_bin launched TWICE (idempotent). t_bin = dur_us - 454.
    hipLaunchKernelGGL(k_bin, dim3(B1), dim3(TPB), 0, stream,
                       (const float4*)x, payload, pfxT, n);
    hipLaunchKernelGGL(k_bin, dim3(B1), dim3(TPB), 0, stream,
                       (const float4*)x, payload, pfxT, n);
    hipLaunchKernelGGL(k_accum, dim3(NG * SLICES), dim3(ATPB), 0, stream,
                       payload, pfxT, partial, n);
    hipLaunchKernelGGL(k_out, dim3((NG * HCELLS) / 256), dim3(256), 0, stream,
                       partial, out);
}

// Round 8
// 410.494 us; speedup vs baseline: 1.2723x; 1.2723x over previous
//
#include <hip/hip_runtime.h>
#include <stdint.h>

// Round 15: fix k_accum's WAVE-level dt imbalance (the real r9-r13 invariant).
//  r14 measured: t_bin = 522-454 = 68us (near its 53us floor) => t_accum
//  ~128us. Why invariant: t sorted => each chunk has ONE dt => group g is
//  non-empty only in the contiguous QUARTER of rows with matching dt.
//  Busy-wave count was ~2400 in EVERY round: r9-r11 (contiguous slices:
//  2/8 slices busy x 8 waves), r12/r13 (strided slices but contiguous
//  per-wave spans: 2/8 waves busy x 1200 blocks). Latency-bound chain
//  (seg load -> LDS atomic) with only 2 busy waves/SIMD of cover.
//  Fix: 32-row tiles, wave (s,wid) takes T = tq*64 + wid*8 + s, tq=0..3 --
//  one tile per dt-quarter => ALL 9600 waves busy (~1760 events each),
//  8 busy waves/SIMD. pfxT loads stay coalesced (contiguous 32-row tiles;
//  lanes 0-31 load begins, 32-63 load ends).
//  k_bin: single launch again, unchanged from r13 (68us, ~1.3x floor).
//
// payload word: tok<<24 | c<<20 | q20(wt), c = bucket&15. hist key = w>>20.
// ws: payload u32*n | pfxT u16[NG][B1] | partial u64[SLICES][NG][4096]

#define TPB 256
#define B1 8192
#define CHUNK 2048                 // B1*CHUNK = 2^24 = n
#define EVT (CHUNK / TPB)          // 8 events per thread (spill-free stash)
#define NBUCKET 2400
#define GACC 16                    // buckets per group
#define NG (NBUCKET / GACC)        // 150 groups
#define SLICES 8
#define HCELLS (GACC * 256)        // 4096 cells per group
#define ATPB 512                   // k_accum block size (8 waves)
#define NTILE (B1 / 32)            // 256 tiles of 32 rows
#define OUT_CH_STRIDE 76800        // 256*300
#define OUT_DP_STRIDE 153600       // 2*256*300

// classify: quotient-reuse form. rem = v - floor(v/c)*c is exactly jnp.mod.
__device__ __forceinline__ void classify_full(const float4 e, const float t0,
                                              const float d_wt, const float d_dt,
                                              int& bucket, int& tok, float& wt) {
    const float c1 = (float)(319.0 / 20.0 + 1e-4);   // W/PW + B
    const float c2 = (float)(239.0 / 15.0 + 1e-4);   // H/PH + B
    const float fy = floorf(e.y / c1);
    const float fz = floorf(e.z / c2);
    const float remy = e.y - fy * c1;
    const float remz = e.z - fz * c2;
    const int pos = (int)(fy + fz * 20.0f);
    tok = (int)(floorf(remy) + floorf(remz) * 16.0f);
    const int dt = (int)floorf(4.0f * (e.x - t0) / d_dt);
    const int p  = (int)e.w;
    bucket = (dt * 2 + p) * 300 + pos;
    wt = (e.x - t0) / d_wt;
}

__global__ __launch_bounds__(TPB) void k_bin(const float4* __restrict__ x,
                                             uint32_t* __restrict__ payload,
                                             uint16_t* __restrict__ pfxT,
                                             int n) {
    __shared__ uint32_t stage[CHUNK];     // 8 KB
    __shared__ uint32_t cnt[NG];          // 600 B: group counts, then prefixes
    __shared__ uint32_t wsum[TPB / 64];   // 4 waves

    if (threadIdx.x < NG) cnt[threadIdx.x] = 0;
    __syncthreads();

    const float* xf = (const float*)x;
    const float t0 = xf[0];
    const float tlast = xf[(size_t)(n - 1) * 4];
    const float d_wt = tlast - t0 + 1e-4f;
    const float d_dt = tlast - t0 + 1.0f;

    const int beg = blockIdx.x * CHUNK;
    const bool full = (beg + CHUNK <= n);

    // phase 1: classify once; atomicAdd returns within-group rank (stash it)
    uint32_t pk[EVT];
    uint32_t bk[EVT];
    if (full) {
        #pragma unroll
        for (int k = 0; k < EVT; ++k) {
            float4 e = x[beg + threadIdx.x + k * TPB];
            int bucket, tok; float wt;
            classify_full(e, t0, d_wt, d_dt, bucket, tok, wt);
            uint32_t q = (uint32_t)(wt * 1048576.0f);          // q20
            q = q > 1048575u ? 1048575u : q;
            pk[k] = ((uint32_t)tok << 24) | ((uint32_t)(bucket & 15) << 20) | q;
            const int g = bucket >> 4;                         // /16 = group
            uint32_t rank = atomicAdd(&cnt[g], 1u);
            bk[k] = (uint32_t)g | (rank << 8);                 // group:8 rank:11
        }
    } else {
        #pragma unroll
        for (int k = 0; k < EVT; ++k) {
            const int i = beg + threadIdx.x + k * TPB;
            if (i < n) {
                float4 e = x[i];
                int bucket, tok; float wt;
                classify_full(e, t0, d_wt, d_dt, bucket, tok, wt);
                uint32_t q = (uint32_t)(wt * 1048576.0f);
                q = q > 1048575u ? 1048575u : q;
                pk[k] = ((uint32_t)tok << 24) | ((uint32_t)(bucket & 15) << 20) | q;
                const int g = bucket >> 4;
                uint32_t rank = atomicAdd(&cnt[g], 1u);
                bk[k] = (uint32_t)g | (rank << 8);
            } else {
                bk[k] = 0xFFFFFFFFu;
            }
        }
    }
    __syncthreads();

    // phase 2: exclusive scan of 150 group counts (threads 0..149)
    const uint32_t c = (threadIdx.x < NG) ? cnt[threadIdx.x] : 0u;
    uint32_t inc = c;
    #pragma unroll
    for (int off = 1; off < 64; off <<= 1) {
        uint32_t u = __shfl_up(inc, off, 64);
        if ((threadIdx.x & 63) >= off) inc += u;
    }
    const int wid = threadIdx.x >> 6, lid = threadIdx.x & 63;
    if (lid == 63) wsum[wid] = inc;
    __syncthreads();
    uint32_t woff = 0;
    for (int w = 0; w < wid; ++w) woff += wsum[w];
    const uint32_t excl = woff + inc - c;

    if (threadIdx.x < NG) {
        cnt[threadIdx.x] = excl;             // group start (read-only below)
        pfxT[(size_t)threadIdx.x * B1 + blockIdx.x] = (uint16_t)excl;
    }
    __syncthreads();

    // phase 3: plain indexed store (rank came from the phase-1 atomic)
    if (full) {
        #pragma unroll
        for (int k = 0; k < EVT; ++k)
            stage[cnt[bk[k] & 0xFFu] + (bk[k] >> 8)] = pk[k];
    } else {
        #pragma unroll
        for (int k = 0; k < EVT; ++k)
            if (bk[k] != 0xFFFFFFFFu)
                stage[cnt[bk[k] & 0xFFu] + (bk[k] >> 8)] = pk[k];
    }
    __syncthreads();

    // phase 4: coalesced LDS -> global writeout
    const int end = min(beg + CHUNK, n);
    const int cntE = end > beg ? end - beg : 0;
    uint32_t* pbase = payload + (size_t)blockIdx.x * CHUNK;
    const int n4 = cntE >> 2;
    const uint4* s4 = (const uint4*)stage;
    uint4* g4 = (uint4*)pbase;
    for (int i = threadIdx.x; i < n4; i += TPB) g4[i] = s4[i];
    for (int i = (n4 << 2) + threadIdx.x; i < cntE; i += TPB) pbase[i] = stage[i];
}

// One block per (group, slice): 150 x 8 = 1200 blocks, 32 KB LDS hist,
// 4 blocks/CU. Rows in 32-row tiles; wave (s,wid) owns tiles
// T = tq*64 + wid*8 + s (tq=0..3) -- ONE tile per dt-quarter, so the
// group's single busy quarter gives EVERY wave exactly one busy tile
// (~1760 events). 16-lane quarters stream each row's payload span.
__global__ __launch_bounds__(ATPB) void k_accum(const uint32_t* __restrict__ payload,
                                                const uint16_t* __restrict__ pfxT,
                                                unsigned long long* __restrict__ partial,
                                                int n) {
    const int g = blockIdx.x >> 3;
    const int s = blockIdx.x & 7;

    __shared__ unsigned long long hist[HCELLS];   // 32 KB: (tok*16+c) -> cnt<<40 | q20sum
    for (int i = threadIdx.x; i < HCELLS; i += ATPB) hist[i] = 0ULL;
    __syncthreads();

    const uint16_t* colb = pfxT + (size_t)g * B1;
    const bool last = (g == NG - 1);
    const uint16_t* cole = colb + B1;             // valid iff !last

    const int wid = threadIdx.x >> 6, lid = threadIdx.x & 63;
    const int q4 = lid >> 4;                      // quarter 0..3
    const int ql = lid & 15;

    #pragma unroll
    for (int tq = 0; tq < 4; ++tq) {
        const int T = tq * 64 + wid * 8 + s;      // tile: rows [T*32, T*32+32)
        const int rowt = T * 32 + (lid & 31);
        // lanes 0-31: segment begins; lanes 32-63: segment ends
        uint32_t v;
        if (lid < 32) {
            v = colb[rowt];
        } else if (!last) {
            v = cole[rowt];
        } else {
            int rc = n - rowt * CHUNK;
            v = rc < 0 ? 0 : (rc > CHUNK ? CHUNK : rc);
        }
        for (int r = 0; r < 32; r += 4) {
            const int rr = r + q4;
            const uint32_t sb = __shfl(v, rr, 64);
            const uint32_t se = __shfl(v, 32 + rr, 64);
            const uint32_t* seg = payload + (size_t)(T * 32 + rr) * CHUNK;
            for (uint32_t j = sb + ql; j < se; j += 16) {
                const uint32_t w = seg[j];
                atomicAdd(&hist[w >> 20],
                          (1ULL << 40) | (unsigned long long)(w & 0xFFFFFu));
            }
        }
    }
    __syncthreads();

    // coalesced partial writeout (every cell written -> no ws pre-zero)
    unsigned long long* pp = partial + ((size_t)s * NG + g) * HCELLS;
    for (int i = threadIdx.x; i < HCELLS; i += ATPB) pp[i] = hist[i];
}

// Sum 8 partials per cell; coalesced reads AND writes (consecutive cells ->
// consecutive pos because key = tok*16 + c). 614,400 cells, each out written
// exactly once -> no out memset.
__global__ __launch_bounds__(256) void k_out(const unsigned long long* __restrict__ partial,
                                             float* __restrict__ out) {
    const int i = blockIdx.x * 256 + threadIdx.x;   // cell id
    unsigned long long v = 0ULL;
    #pragma unroll
    for (int s = 0; s < SLICES; ++s)
        v += partial[(size_t)s * (NG * HCELLS) + i];
    const int g = i >> 12;
    const int idx = i & 4095;
    const int tok = idx >> 4;
    const int c = idx & 15;
    const int b = g * GACC + c;
    const int pos = b % 300;
    const int dp = b / 300;
    const float cntf = (float)(uint32_t)(v >> 40);
    const float wts  = (float)(v & ((1ULL << 40) - 1)) * (1.0f / 1048576.0f);
    const int base0 = dp * OUT_DP_STRIDE + tok * 300 + pos;
    out[base0] = cntf;                     // channel 0: count
    out[base0 + OUT_CH_STRIDE] = wts;      // channel 1: wt sum
}

// ---- fallback (ws too small / n out of range) ----
__global__ __launch_bounds__(256) void e2src_hist_atomic(const float4* __restrict__ x,
                                                         float* __restrict__ out, int n) {
    const float* xf = (const float*)x;
    const float t0 = xf[0];
    const float tlast = xf[(size_t)(n - 1) * 4];
    const float d_wt = tlast - t0 + 1e-4f;
    const float d_dt = tlast - t0 + 1.0f;
    int i = blockIdx.x * blockDim.x + threadIdx.x;
    const int stride = gridDim.x * blockDim.x;
    for (; i < n; i += stride) {
        float4 e = x[i];
        int bucket, tok; float wt;
        classify_full(e, t0, d_wt, d_dt, bucket, tok, wt);
        const int dp = bucket / 300, pos = bucket % 300;
        const int base = dp * OUT_DP_STRIDE + tok * 300 + pos;
        unsafeAtomicAdd(out + base, 1.0f);
        unsafeAtomicAdd(out + base + OUT_CH_STRIDE, wt);
    }
}

extern "C" void kernel_launch(void* const* d_in, const int* in_sizes, int n_in,
                              void* d_out, int out_size, void* d_ws, size_t ws_size,
                              hipStream_t stream) {
    const float* x = (const float*)d_in[0];
    float* out = (float*)d_out;
    const int n = in_sizes[0] / 4;

    const size_t payload_bytes = ((size_t)n * 4u + 7u) & ~(size_t)7u;
    const size_t pfx_bytes = (size_t)B1 * NG * 2u;                 // 2,457,600
    const size_t part_bytes = (size_t)SLICES * NG * HCELLS * 8u;   // 39,321,600
    const size_t need = payload_bytes + pfx_bytes + part_bytes;

    if (ws_size < need || n > B1 * CHUNK || n <= 0) {
        hipMemsetAsync(d_out, 0, (size_t)out_size * sizeof(float), stream);
        if (n > 0)
            hipLaunchKernelGGL(e2src_hist_atomic, dim3(8192), dim3(256), 0, stream,
                               (const float4*)x, out, n);
        return;
    }

    uint32_t* payload = (uint32_t*)d_ws;
    uint16_t* pfxT = (uint16_t*)((char*)d_ws + payload_bytes);
    unsigned long long* partial =
        (unsigned long long*)((char*)d_ws + payload_bytes + pfx_bytes);

    hipLaunchKernelGGL(k_bin, dim3(B1), dim3(TPB), 0, stream,
                       (const float4*)x, payload, pfxT, n);
    hipLaunchKernelGGL(k_accum, dim3(NG * SLICES), dim3(ATPB), 0, stream,
                       payload, pfxT, partial, n);
    hipLaunchKernelGGL(k_out, dim3((NG * HCELLS) / 256), dim3(256), 0, stream,
                       partial, out);
}